// Round 5
// baseline (172.277 us; speedup 1.0000x reference)
//
#include <hip/hip_runtime.h>

// Problem: B=8, S=2048, H=1024, D=64. fp32 in, fp32 out.
// out = softmax_causal(q k^T) / sqrt(H) @ v   (softmax FIRST, then /32)

typedef float     f32x4 __attribute__((ext_vector_type(4)));
typedef _Float16  f16x8 __attribute__((ext_vector_type(8)));
typedef _Float16  f16x4 __attribute__((ext_vector_type(4)));

#define L2E 1.44269504088896340736f

// ---------------------------------------------------------------------------
// Kernel 1: pack W{q,k,v} into MFMA B-fragment order (f16) via LDS transpose.
// Frag (kstep*12+nt)*64+lane holds 8 f16: W[n=nt*16+(lane&15)][k=kstep*32+(lane>>4)*8+j]
__global__ __launch_bounds__(256) void wt_prep(const float* __restrict__ Wq,
                                               const float* __restrict__ Wk,
                                               const float* __restrict__ Wv,
                                               _Float16* __restrict__ WtF) {
  const int w  = blockIdx.x >> 4;              // which W
  const int kt = blockIdx.x & 15;              // k-tile of 64
  const float* src = (w == 0) ? Wq : (w == 1 ? Wk : Wv);
  __shared__ _Float16 ls[64][72];
  const int t = threadIdx.x;
  {
    int rr = t >> 4;
    int c4 = (t & 15) * 4;
    #pragma unroll
    for (int ri = 0; ri < 4; ++ri) {
      int k = rr + ri * 16;
      f32x4 f = *(const f32x4*)&src[(size_t)(kt * 64 + k) * 64 + c4];
      #pragma unroll
      for (int j = 0; j < 4; ++j) ls[k][c4 + j] = (_Float16)f[j];
    }
  }
  __syncthreads();
  const int lane = t & 63, l16 = lane & 15, quad = lane >> 4;
  #pragma unroll
  for (int h = 0; h < 2; ++h) {
    int fid     = h * 4 + (t >> 6);
    int kstep_l = fid >> 2;
    int ntl     = fid & 3;
    int nt      = w * 4 + ntl;
    int kstep   = kt * 2 + kstep_l;
    f16x8 o;
    #pragma unroll
    for (int j = 0; j < 8; ++j) o[j] = ls[kstep_l * 32 + quad * 8 + j][ntl * 16 + l16];
    *(f16x8*)&WtF[((size_t)(kstep * 12 + nt) * 64 + lane) * 8] = o;
  }
}

// ---------------------------------------------------------------------------
// Kernel 2: QKV projection. Grid 512 (M-tile=32), 512 threads (8 waves =
// 2 mhalf x 4 ngrp of 3 n-tiles). Whole 32x1024 x-tile staged once
// (XOR-swizzled 64KB LDS, single barrier); each wave streams 96 coalesced
// B-frag loads + 96 MFMAs, unroll 8 -> up to 24 B loads in flight.
__global__ __launch_bounds__(512, 4) void qkv_gemm(const float* __restrict__ x,
                                                   const _Float16* __restrict__ WtF,
                                                   const float* __restrict__ bq,
                                                   const float* __restrict__ bk,
                                                   const float* __restrict__ bv,
                                                   _Float16* __restrict__ qo,
                                                   _Float16* __restrict__ ko,
                                                   _Float16* __restrict__ vt) {
  __shared__ _Float16 xs[32 * 1024];           // 64 KB
  const int tid  = threadIdx.x;
  const int wave = tid >> 6, lane = tid & 63;
  const int l16  = lane & 15, quad = lane >> 4;
  const int mhalf = wave >> 2;                 // 0..1
  const int ngrp  = wave & 3;                  // 0..3, owns n-tiles ngrp*3 .. +2
  const int m0    = blockIdx.x * 32;

  {                                            // stage x (fp32->f16), coalesced
    int row   = tid >> 4;                      // 0..31
    int cbase = (tid & 15) * 4;
    const float* xrow = x + (size_t)(m0 + row) * 1024;
    int key = row & 7;
    #pragma unroll
    for (int j = 0; j < 16; ++j) {
      int col = cbase + j * 64;
      f32x4 f = *(const f32x4*)&xrow[col];
      f16x4 hh;
      #pragma unroll
      for (int e = 0; e < 4; ++e) hh[e] = (_Float16)f[e];
      int g   = col >> 3;                      // granule 0..127
      int sub = col & 7;
      *(f16x4*)&xs[(size_t)row * 1024 + (size_t)((g ^ key) << 3) + sub] = hh;
    }
  }
  __syncthreads();

  f32x4 acc0 = (f32x4){0.f,0.f,0.f,0.f};
  f32x4 acc1 = (f32x4){0.f,0.f,0.f,0.f};
  f32x4 acc2 = (f32x4){0.f,0.f,0.f,0.f};
  const int arow = mhalf * 16 + l16;
  const _Float16* abase = xs + (size_t)arow * 1024;
  const int akey = arow & 7;
  const _Float16* wbase = WtF + ((size_t)(ngrp * 3) * 64 + lane) * 8;

  #pragma unroll 8
  for (int kstep = 0; kstep < 32; ++kstep) {
    f16x8 a = *(const f16x8*)(abase + (((kstep * 4 + quad) ^ akey) << 3));
    const _Float16* wk = wbase + (size_t)kstep * (12 * 64 * 8);
    f16x8 b0 = *(const f16x8*)(wk);
    f16x8 b1 = *(const f16x8*)(wk + 512);
    f16x8 b2 = *(const f16x8*)(wk + 1024);
    acc0 = __builtin_amdgcn_mfma_f32_16x16x32_f16(a, b0, acc0, 0, 0, 0);
    acc1 = __builtin_amdgcn_mfma_f32_16x16x32_f16(a, b1, acc1, 0, 0, 0);
    acc2 = __builtin_amdgcn_mfma_f32_16x16x32_f16(a, b2, acc2, 0, 0, 0);
  }

  f32x4 accs[3] = {acc0, acc1, acc2};
  #pragma unroll
  for (int i = 0; i < 3; ++i) {
    int nt  = ngrp * 3 + i;
    int col = nt * 16 + l16;
    float bias = (nt < 4) ? bq[col] : (nt < 8) ? bk[col - 64] : bv[col - 128];
    #pragma unroll
    for (int r = 0; r < 4; ++r) {
      int m = m0 + mhalf * 16 + quad * 4 + r;  // global row = b*2048+s
      _Float16 hv = (_Float16)(accs[i][r] + bias);
      if (nt < 4)      qo[(size_t)m * 64 + col] = hv;
      else if (nt < 8) ko[(size_t)m * 64 + (col - 64)] = hv;
      else {                                   // v stored transposed: vt[b][d][s]
        int b = m >> 11, s = m & 2047;
        vt[((size_t)b * 64 + (col - 128)) * 2048 + s] = hv;
      }
    }
  }
}

// ---------------------------------------------------------------------------
// Kernel 3: causal attention. Fat waves: each wave owns a 16q x 256kv slab
// (32 independent k-loads + 32 QK MFMAs in flight; ONE softmax over 64
// in-lane values + 2 shuffles; 8KB P tile; 32 v-loads + 32 PV MFMAs).
// Block = 4 waves = 1024 kv. qt<64: single block -> writes out directly.
// qt>=64: 2 blocks -> f16 partials, merged by attn_merge.
// Scores kv-major: C col = q, row = kv.
__global__ __launch_bounds__(256, 3) void attn(const _Float16* __restrict__ q,
                                               const _Float16* __restrict__ k,
                                               const _Float16* __restrict__ vt,
                                               _Float16* __restrict__ po,
                                               float* __restrict__ pm,
                                               float* __restrict__ pl,
                                               float* __restrict__ out) {
  const int bx = blockIdx.x, b = blockIdx.y;
  int qt, s;
  if (bx < 128) { qt = 64 + (bx >> 1); s = bx & 1; }   // heavy (1024-kv) first
  else          { qt = 191 - bx;       s = 0; }        // qt 63..0
  const int q0 = qt * 16, kvend = q0 + 16;
  const int tid  = threadIdx.x;
  const int wave = tid >> 6, lane = tid & 63;
  const int l16  = lane & 15, quad = lane >> 4;
  const int kv0  = s * 1024 + wave * 256;
  const int vlen = kvend - kv0;                        // may be <=0 (empty wave)

  __shared__ _Float16 Pbuf[4][16 * 264];               // per-wave P [q][kv], pad 264
  __shared__ float mw[4][16], lw[4][16];
  _Float16* Pw = &Pbuf[wave][0];

  float m = -1e30f, l = 0.f;
  f32x4 o[4];
  #pragma unroll
  for (int i = 0; i < 4; ++i) o[i] = (f32x4){0.f, 0.f, 0.f, 0.f};

  if (vlen > 0) {
    const _Float16* qb = q  + (size_t)b * 2048 * 64;
    const _Float16* kb = k  + (size_t)b * 2048 * 64;
    const _Float16* vb = vt + (size_t)b * 64 * 2048;
    // Q as B-operand: B[k=d=quad*8+j][n=q=l16]
    f16x8 qf0 = *(const f16x8*)&qb[(size_t)(q0 + l16) * 64 + quad * 8];
    f16x8 qf1 = *(const f16x8*)&qb[(size_t)(q0 + l16) * 64 + 32 + quad * 8];

    // --- QK^T over 16 kv-tiles (K as A: A[m=kv=l16][k=d])
    f32x4 sc[16];
    #pragma unroll
    for (int t = 0; t < 16; ++t) {
      const int kvt = kv0 + t * 16;
      if (kvt < kvend) {
        f16x8 kf0 = *(const f16x8*)&kb[(size_t)(kvt + l16) * 64 + quad * 8];
        f16x8 kf1 = *(const f16x8*)&kb[(size_t)(kvt + l16) * 64 + 32 + quad * 8];
        f32x4 c = (f32x4){0.f, 0.f, 0.f, 0.f};
        c = __builtin_amdgcn_mfma_f32_16x16x32_f16(kf0, qf0, c, 0, 0, 0);
        c = __builtin_amdgcn_mfma_f32_16x16x32_f16(kf1, qf1, c, 0, 0, 0);
        if (kvt == q0) {                       // diagonal tile: mask skv > sq
          #pragma unroll
          for (int rr = 0; rr < 4; ++rr)
            if (quad * 4 + rr > l16) c[rr] = -1e30f;
        }
        sc[t] = c;
      } else {
        sc[t] = (f32x4){-1e30f, -1e30f, -1e30f, -1e30f};
      }
    }
    // --- softmax over kv (in-lane 64 values + 2 shuffles; col q = l16 fixed)
    float mx = sc[0][0];
    #pragma unroll
    for (int t = 0; t < 16; ++t)
      #pragma unroll
      for (int rr = 0; rr < 4; ++rr) mx = fmaxf(mx, sc[t][rr]);
    mx = fmaxf(mx, __shfl_xor(mx, 16, 64));
    mx = fmaxf(mx, __shfl_xor(mx, 32, 64));
    m = mx;
    float sum = 0.f;
    #pragma unroll
    for (int t = 0; t < 16; ++t) {
      #pragma unroll
      for (int rr = 0; rr < 4; ++rr) {
        float e = exp2f((sc[t][rr] - m) * L2E);          // masked/invalid -> 0
        sc[t][rr] = e;
        sum += e;
      }
    }
    sum += __shfl_xor(sum, 16, 64);
    sum += __shfl_xor(sum, 32, 64);
    l = sum;
    // --- P -> LDS [q=l16][kv local], f16x4 per tile (rr = consecutive kv)
    #pragma unroll
    for (int t = 0; t < 16; ++t) {
      f16x4 ph;
      #pragma unroll
      for (int rr = 0; rr < 4; ++rr) ph[rr] = (_Float16)sc[t][rr];
      *(f16x4*)&Pw[l16 * 264 + t * 16 + quad * 4] = ph;
    }
    asm volatile("s_waitcnt lgkmcnt(0)" ::: "memory");   // per-wave DS drain
    // --- PV over valid 32-kv chunks: O^T[d][q] += Vt[d][kv] * P[kv][q]
    const int nck = (vlen >= 256) ? 8 : ((vlen + 31) >> 5);
    #pragma unroll
    for (int c = 0; c < 8; ++c) {
      if (c < nck) {
        f16x8 pfr = *(const f16x8*)&Pw[l16 * 264 + c * 32 + quad * 8];
        #pragma unroll
        for (int dt = 0; dt < 4; ++dt) {
          f16x8 vf = *(const f16x8*)&vb[(size_t)(dt * 16 + l16) * 2048 + kv0 + c * 32 + quad * 8];
          o[dt] = __builtin_amdgcn_mfma_f32_16x16x32_f16(vf, pfr, o[dt], 0, 0, 0);
        }
      }
    }
  }

  // --- publish per-wave partials; ow aliases this wave's own P region
  float* owp = (float*)Pw;                     // [16 q][68 d] f32 (4352 B < 8448 B)
  #pragma unroll
  for (int dt = 0; dt < 4; ++dt)
    *(f32x4*)&owp[l16 * 68 + dt * 16 + quad * 4] = o[dt];   // q=l16, d=dt*16+quad*4+rr
  if (quad == 0) { mw[wave][l16] = m; lw[wave][l16] = l; }
  __syncthreads();

  // --- merge 4 waves; thread t -> q = t>>4, d = (t&15)*4 .. +3
  {
    const int qr = tid >> 4, dg = (tid & 15) * 4;
    float m0v = mw[0][qr], m1v = mw[1][qr], m2v = mw[2][qr], m3v = mw[3][qr];
    float M = fmaxf(fmaxf(m0v, m1v), fmaxf(m2v, m3v));
    float L = 0.f;
    f32x4 O = (f32x4){0.f, 0.f, 0.f, 0.f};
    #pragma unroll
    for (int w = 0; w < 4; ++w) {
      float mwv = (w == 0) ? m0v : (w == 1) ? m1v : (w == 2) ? m2v : m3v;
      float wt = exp2f((mwv - M) * L2E);       // empty wave (m=-1e30) -> 0
      L += wt * lw[w][qr];
      f32x4 ov = *(const f32x4*)&((float*)&Pbuf[w][0])[qr * 68 + dg];
      #pragma unroll
      for (int j = 0; j < 4; ++j) O[j] += wt * ov[j];
    }
    if (qt < 64) {                             // single split: final output
      float inv = 1.0f / (L * 32.0f);          // sqrt(H)=32 applied AFTER softmax
      f32x4 res;
      #pragma unroll
      for (int j = 0; j < 4; ++j) res[j] = O[j] * inv;
      *(f32x4*)&out[((size_t)b * 2048 + q0 + qr) * 64 + dg] = res;
    } else {                                   // 2 splits: f16 partial
      size_t pid = (size_t)b * 128 + bx;
      f16x4 oh;
      #pragma unroll
      for (int j = 0; j < 4; ++j) oh[j] = (_Float16)O[j];
      *(f16x4*)&po[pid * 1024 + (size_t)qr * 64 + dg] = oh;
      if ((tid & 15) == 0) { pm[pid * 16 + qr] = M; pl[pid * 16 + qr] = L; }
    }
  }
}

// ---------------------------------------------------------------------------
// Kernel 4: merge the 2 splits of q-tiles 64..127, normalize, write out.
__global__ __launch_bounds__(256) void attn_merge(const _Float16* __restrict__ po,
                                                  const float* __restrict__ pm,
                                                  const float* __restrict__ pl,
                                                  float* __restrict__ out) {
  const int qt = 64 + blockIdx.x, b = blockIdx.y;
  const size_t pid0 = (size_t)b * 128 + (qt - 64) * 2, pid1 = pid0 + 1;
  const int t = threadIdx.x, qr = t >> 4, dg = (t & 15) * 4;

  float m0 = pm[pid0 * 16 + qr], m1 = pm[pid1 * 16 + qr];
  float M  = fmaxf(m0, m1);
  float w0 = exp2f((m0 - M) * L2E), w1 = exp2f((m1 - M) * L2E);
  float L  = w0 * pl[pid0 * 16 + qr] + w1 * pl[pid1 * 16 + qr];
  f16x4 o0 = *(const f16x4*)&po[pid0 * 1024 + (size_t)qr * 64 + dg];
  f16x4 o1 = *(const f16x4*)&po[pid1 * 1024 + (size_t)qr * 64 + dg];
  float inv = 1.0f / (L * 32.0f);              // sqrt(H)=32 applied AFTER softmax
  f32x4 res;
  #pragma unroll
  for (int j = 0; j < 4; ++j)
    res[j] = (w0 * (float)o0[j] + w1 * (float)o1[j]) * inv;
  *(f32x4*)&out[((size_t)b * 2048 + qt * 16 + qr) * 64 + dg] = res;
}

// ---------------------------------------------------------------------------
extern "C" void kernel_launch(void* const* d_in, const int* in_sizes, int n_in,
                              void* d_out, int out_size, void* d_ws, size_t ws_size,
                              hipStream_t stream) {
  const float* x  = (const float*)d_in[0];
  const float* Wq = (const float*)d_in[1];
  const float* bq = (const float*)d_in[2];
  const float* Wk = (const float*)d_in[3];
  const float* bk = (const float*)d_in[4];
  const float* Wv = (const float*)d_in[5];
  const float* bv = (const float*)d_in[6];
  float* out = (float*)d_out;

  // ws: WtF 384KB | q 2MB | k 2MB | vt 2MB | po 2MB f16 | pm/pl 128KB f32
  _Float16* WtF = (_Float16*)d_ws;
  _Float16* qo  = WtF + 192 * 1024;
  _Float16* ko  = qo + 16384 * 64;
  _Float16* vt  = ko + 16384 * 64;
  _Float16* po  = vt + 8 * 64 * 2048;
  float*    pm  = (float*)(po + (size_t)1024 * 1024);
  float*    pl  = pm + 1024 * 16;

  hipLaunchKernelGGL(wt_prep,    dim3(48),      dim3(256), 0, stream, Wq, Wk, Wv, WtF);
  hipLaunchKernelGGL(qkv_gemm,   dim3(512),     dim3(512), 0, stream, x, WtF, bq, bk, bv, qo, ko, vt);
  hipLaunchKernelGGL(attn,       dim3(192, 8),  dim3(256), 0, stream, qo, ko, vt, po, pm, pl, out);
  hipLaunchKernelGGL(attn_merge, dim3(64, 8),   dim3(256), 0, stream, po, pm, pl, out);
}